// Round 2
// baseline (159.604 us; speedup 1.0000x reference)
//
#include <hip/hip_runtime.h>
#include <hip/hip_bf16.h>

// B=16, N=1024, M=8192.
//   d[b,n,m] = || binder[b,n,:] - target[m,:] ||
//   attract[b] = mean of 204 smallest (min_m d) over n;  repel[b] = sum relu(3-d)^2
//   out[b] = 10*attract + 5*repel
//
// Kernel 1 (VALU-issue bound): grid (MC=32, B=16), 256 thr. Each thread owns
//   4 binder points in registers; 256 targets staged in LDS as float4 so ONE
//   broadcast ds_read_b128 serves 4 pairs (R1 showed ds_read_b32 issue was the
//   64us bottleneck: 6.3M ds instr ~ 59us). Clash path guarded by
//   __any(min4<9) to keep v_sqrt off the hot path (~1e-4 of pairs clash).
// Kernel 2: per-batch exact sum-of-204-smallest via 4-pass 256-bin radix
//   select on float bits (monotonic for non-negative floats) — replaces the
//   55-barrier bitonic sort.

#define BB 16
#define NN 1024
#define MM 8192
#define MT 256          // targets per chunk
#define MC (MM / MT)    // 32 m-chunks
#define KSEL 204        // int(0.2 * 1024)

__global__ __launch_bounds__(256) void binder_pair_kernel(
    const float* __restrict__ binder,   // [B, N, 3]
    const float* __restrict__ target,   // [M, 3]
    float* __restrict__ min_part,       // [B, N, MC] (min d^2 per chunk)
    float* __restrict__ repel_part)     // [B, MC]
{
    __shared__ float4 t4[MT];
    __shared__ float wred[4];

    const int mc  = blockIdx.x;
    const int b   = blockIdx.y;
    const int tid = threadIdx.x;

    if (tid < MT) {
        const float* tp = target + (mc * MT + tid) * 3;
        t4[tid] = make_float4(tp[0], tp[1], tp[2], 0.0f);
    }
    __syncthreads();

    // 4 binder points per thread: n = 4*tid + {0,1,2,3}; 48B contiguous/lane.
    const float* bp = binder + ((size_t)b * NN + tid * 4) * 3;
    const float4 f0 = ((const float4*)bp)[0];
    const float4 f1 = ((const float4*)bp)[1];
    const float4 f2 = ((const float4*)bp)[2];
    const float x0 = f0.x, y0 = f0.y, z0 = f0.z;
    const float x1 = f0.w, y1 = f1.x, z1 = f1.y;
    const float x2 = f1.z, y2 = f1.w, z2 = f2.x;
    const float x3 = f2.y, y3 = f2.z, z3 = f2.w;

    float m0 = 3.4e38f, m1 = 3.4e38f, m2 = 3.4e38f, m3 = 3.4e38f;
    float repel = 0.0f;

#pragma unroll 4
    for (int m = 0; m < MT; ++m) {
        const float4 t = t4[m];   // wave-uniform addr -> broadcast b128
        const float dx0 = x0 - t.x, dy0 = y0 - t.y, dz0 = z0 - t.z;
        const float dx1 = x1 - t.x, dy1 = y1 - t.y, dz1 = z1 - t.z;
        const float dx2 = x2 - t.x, dy2 = y2 - t.y, dz2 = z2 - t.z;
        const float dx3 = x3 - t.x, dy3 = y3 - t.y, dz3 = z3 - t.z;
        const float d0 = fmaf(dx0, dx0, fmaf(dy0, dy0, dz0 * dz0));
        const float d1 = fmaf(dx1, dx1, fmaf(dy1, dy1, dz1 * dz1));
        const float d2 = fmaf(dx2, dx2, fmaf(dy2, dy2, dz2 * dz2));
        const float d3 = fmaf(dx3, dx3, fmaf(dy3, dy3, dz3 * dz3));
        m0 = fminf(m0, d0);
        m1 = fminf(m1, d1);
        m2 = fminf(m2, d2);
        m3 = fminf(m3, d3);
        const float mm = fminf(fminf(d0, d1), fminf(d2, d3));
        if (__any(mm < 9.0f)) {        // rare clash path (taken ~4% of iters)
            const float c0 = fmaxf(3.0f - sqrtf(d0), 0.0f);
            const float c1 = fmaxf(3.0f - sqrtf(d1), 0.0f);
            const float c2 = fmaxf(3.0f - sqrtf(d2), 0.0f);
            const float c3 = fmaxf(3.0f - sqrtf(d3), 0.0f);
            repel = fmaf(c0, c0, repel);
            repel = fmaf(c1, c1, repel);
            repel = fmaf(c2, c2, repel);
            repel = fmaf(c3, c3, repel);
        }
    }

    float* mp = min_part + ((size_t)b * NN + tid * 4) * MC + mc;
    mp[0 * MC] = m0;
    mp[1 * MC] = m1;
    mp[2 * MC] = m2;
    mp[3 * MC] = m3;

    // repel reduce: wave shuffle then 4-slot LDS
#pragma unroll
    for (int off = 32; off > 0; off >>= 1) repel += __shfl_down(repel, off);
    if ((tid & 63) == 0) wred[tid >> 6] = repel;
    __syncthreads();
    if (tid == 0) repel_part[b * MC + mc] = wred[0] + wred[1] + wred[2] + wred[3];
}

__global__ __launch_bounds__(256) void binder_reduce_kernel(
    const float* __restrict__ min_part,    // [B, N, MC]
    const float* __restrict__ repel_part,  // [B, MC]
    float* __restrict__ out)               // [B]
{
    __shared__ int   cnt[256];
    __shared__ float fsum[256];
    __shared__ int   sel_s;

    const int b   = blockIdx.x;
    const int tid = threadIdx.x;

    // fold chunk mins for 4 points, sqrt -> values in registers
    float    v[4];
    unsigned ub[4];
    bool     active[4];
#pragma unroll
    for (int p = 0; p < 4; ++p) {
        const int n = tid * 4 + p;
        const float4* mp = (const float4*)(min_part + ((size_t)b * NN + n) * MC);
        float4 a = mp[0];
#pragma unroll
        for (int c = 1; c < MC / 4; ++c) {
            const float4 q = mp[c];
            a.x = fminf(a.x, q.x); a.y = fminf(a.y, q.y);
            a.z = fminf(a.z, q.z); a.w = fminf(a.w, q.w);
        }
        v[p] = sqrtf(fminf(fminf(a.x, a.y), fminf(a.z, a.w)));
        ub[p] = __float_as_uint(v[p]);   // monotonic: v >= 0
        active[p] = true;
    }

    float total = 0.0f;   // meaningful in tid 0 only
    int   k_rem = KSEL;

    for (int shift = 24; shift >= 0; shift -= 8) {
        cnt[tid] = 0;
        fsum[tid] = 0.0f;
        __syncthreads();
#pragma unroll
        for (int p = 0; p < 4; ++p) {
            if (active[p]) {
                const int bin = (ub[p] >> shift) & 255;
                atomicAdd(&cnt[bin], 1);
                atomicAdd(&fsum[bin], v[p]);
            }
        }
        __syncthreads();
        if (tid == 0) {
            int bsel = 255;
            for (int bb = 0; bb < 256; ++bb) {
                if (cnt[bb] < k_rem) {
                    total += fsum[bb];
                    k_rem -= cnt[bb];
                } else {
                    bsel = bb;
                    break;
                }
            }
            sel_s = bsel;
            if (shift == 0) {
                // all remaining values in bin share all 32 bits -> equal
                total += fsum[bsel] * ((float)k_rem / (float)cnt[bsel]);
            }
        }
        __syncthreads();
        if (shift > 0) {
            const int sel = sel_s;
#pragma unroll
            for (int p = 0; p < 4; ++p)
                active[p] = active[p] && (((ub[p] >> shift) & 255) == sel);
        }
    }

    // repel partials: 32 values, reduce in wave 0
    float r = (tid < MC) ? repel_part[b * MC + tid] : 0.0f;
    if (tid < 64) {
        r += __shfl_down(r, 32);
        r += __shfl_down(r, 16);
        r += __shfl_down(r, 8);
        r += __shfl_down(r, 4);
        r += __shfl_down(r, 2);
        r += __shfl_down(r, 1);
    }
    if (tid == 0) out[b] = 10.0f * (total / (float)KSEL) + 5.0f * r;
}

extern "C" void kernel_launch(void* const* d_in, const int* in_sizes, int n_in,
                              void* d_out, int out_size, void* d_ws, size_t ws_size,
                              hipStream_t stream) {
    const float* binder = (const float*)d_in[0];   // [16,1024,3] fp32
    const float* target = (const float*)d_in[1];   // [8192,3]   fp32
    float* out = (float*)d_out;                    // [16]       fp32

    float* min_part   = (float*)d_ws;  // B*N*MC floats = 2 MiB
    float* repel_part = (float*)((char*)d_ws + (size_t)BB * NN * MC * sizeof(float));

    dim3 g1(MC, BB);   // 32 x 16 = 512 blocks
    binder_pair_kernel<<<g1, 256, 0, stream>>>(binder, target, min_part, repel_part);
    binder_reduce_kernel<<<BB, 256, 0, stream>>>(min_part, repel_part, out);
}

// Round 3
// 106.432 us; speedup vs baseline: 1.4996x; 1.4996x over previous
//
#include <hip/hip_runtime.h>
#include <hip/hip_bf16.h>

// B=16, N=1024, M=8192.
//   d[b,n,m] = || binder[b,n,:] - target[m,:] ||
//   attract[b] = mean of 204 smallest (min_m d) over n;  repel[b] = sum relu(3-d)^2
//   out[b] = 10*attract + 5*repel
//
// R3 changes (R2 post-mortem: pair kernel was latency-bound at 2 waves/SIMD;
// reduce kernel's tid0-serial bin scan was ~90us):
//  - MC=128 chunks -> 2048 blocks = 8 waves/SIMD full occupancy.
//  - chunk-min fold via global atomicMin on uint bits (monotonic for d2>=0,
//    deterministic) -> no [B,N,MC] array, no fold loop in reduce.
//  - clash branch body uses raw v_sqrt (__builtin_amdgcn_sqrtf).
//  - reduce: radix-256 select with PARALLEL scan (8 steps), count-only
//    histograms; sum = sum_{u<T} sqrt(u) + ties*sqrt(T). Exact.

#define BB 16
#define NN 1024
#define MM 8192
#define MT 64           // targets per chunk
#define MC (MM / MT)    // 128 m-chunks
#define KSEL 204        // int(0.2 * 1024)

__global__ __launch_bounds__(256, 8) void binder_pair_kernel(
    const float* __restrict__ binder,   // [B, N, 3]
    const float* __restrict__ target,   // [M, 3]
    unsigned* __restrict__ min_u,       // [B, N] uint bits of min d^2 (pre-init 0xFFFFFFFF)
    float* __restrict__ repel_part)     // [B, MC]
{
    __shared__ float4 t4[MT];
    __shared__ float wred[4];

    const int mc  = blockIdx.x;
    const int b   = blockIdx.y;
    const int tid = threadIdx.x;

    if (tid < MT) {
        const float* tp = target + (mc * MT + tid) * 3;
        t4[tid] = make_float4(tp[0], tp[1], tp[2], 0.0f);
    }
    __syncthreads();

    // 4 binder points per thread; 48B contiguous/lane, 16B-aligned.
    const float* bp = binder + ((size_t)b * NN + tid * 4) * 3;
    const float4 f0 = ((const float4*)bp)[0];
    const float4 f1 = ((const float4*)bp)[1];
    const float4 f2 = ((const float4*)bp)[2];
    const float x0 = f0.x, y0 = f0.y, z0 = f0.z;
    const float x1 = f0.w, y1 = f1.x, z1 = f1.y;
    const float x2 = f1.z, y2 = f1.w, z2 = f2.x;
    const float x3 = f2.y, y3 = f2.z, z3 = f2.w;

    float m0 = 3.4e38f, m1 = 3.4e38f, m2 = 3.4e38f, m3 = 3.4e38f;
    float repel = 0.0f;

#pragma unroll 4
    for (int m = 0; m < MT; ++m) {
        const float4 t = t4[m];   // wave-uniform addr -> broadcast b128
        const float dx0 = x0 - t.x, dy0 = y0 - t.y, dz0 = z0 - t.z;
        const float dx1 = x1 - t.x, dy1 = y1 - t.y, dz1 = z1 - t.z;
        const float dx2 = x2 - t.x, dy2 = y2 - t.y, dz2 = z2 - t.z;
        const float dx3 = x3 - t.x, dy3 = y3 - t.y, dz3 = z3 - t.z;
        const float d0 = fmaf(dx0, dx0, fmaf(dy0, dy0, dz0 * dz0));
        const float d1 = fmaf(dx1, dx1, fmaf(dy1, dy1, dz1 * dz1));
        const float d2 = fmaf(dx2, dx2, fmaf(dy2, dy2, dz2 * dz2));
        const float d3 = fmaf(dx3, dx3, fmaf(dy3, dy3, dz3 * dz3));
        m0 = fminf(m0, d0);
        m1 = fminf(m1, d1);
        m2 = fminf(m2, d2);
        m3 = fminf(m3, d3);
        const float mm = fminf(fminf(d0, d1), fminf(d2, d3));
        if (__any(mm < 9.0f)) {   // clash path: raw v_sqrt, short body
            const float c0 = fmaxf(3.0f - __builtin_amdgcn_sqrtf(d0), 0.0f);
            const float c1 = fmaxf(3.0f - __builtin_amdgcn_sqrtf(d1), 0.0f);
            const float c2 = fmaxf(3.0f - __builtin_amdgcn_sqrtf(d2), 0.0f);
            const float c3 = fmaxf(3.0f - __builtin_amdgcn_sqrtf(d3), 0.0f);
            repel = fmaf(c0, c0, repel);
            repel = fmaf(c1, c1, repel);
            repel = fmaf(c2, c2, repel);
            repel = fmaf(c3, c3, repel);
        }
    }

    // fold chunk mins via deterministic uint atomicMin (bits monotonic, d2>=0)
    unsigned* mp = min_u + (size_t)b * NN + tid * 4;
    atomicMin(&mp[0], __float_as_uint(m0));
    atomicMin(&mp[1], __float_as_uint(m1));
    atomicMin(&mp[2], __float_as_uint(m2));
    atomicMin(&mp[3], __float_as_uint(m3));

    // repel block-reduce: wave shuffle then 4-slot LDS
#pragma unroll
    for (int off = 32; off > 0; off >>= 1) repel += __shfl_down(repel, off);
    if ((tid & 63) == 0) wred[tid >> 6] = repel;
    __syncthreads();
    if (tid == 0) repel_part[b * MC + mc] = wred[0] + wred[1] + wred[2] + wred[3];
}

__global__ __launch_bounds__(256) void binder_reduce_kernel(
    const unsigned* __restrict__ min_u,    // [B, N] bits of min d^2
    const float* __restrict__ repel_part,  // [B, MC]
    float* __restrict__ out)               // [B]
{
    __shared__ int cnt[256];
    __shared__ int bc_bin, bc_rem;
    __shared__ float wred[4];
    __shared__ float wred2[4];

    const int b   = blockIdx.x;
    const int tid = threadIdx.x;

    const uint4 uv = ((const uint4*)(min_u + (size_t)b * NN))[tid];
    unsigned uu[4] = {uv.x, uv.y, uv.z, uv.w};

    // radix-256 select of the KSEL-th smallest bit pattern, MSB-first.
    unsigned prefix = 0u;
    int rem = KSEL;
#pragma unroll
    for (int shift = 24; shift >= 0; shift -= 8) {
        cnt[tid] = 0;
        __syncthreads();
        const unsigned hmask = (shift == 24) ? 0u : (0xFFFFFFFFu << (shift + 8));
#pragma unroll
        for (int p = 0; p < 4; ++p)
            if ((uu[p] & hmask) == (prefix & hmask))
                atomicAdd(&cnt[(uu[p] >> shift) & 255], 1);
        __syncthreads();
        const int orig = cnt[tid];
        // inclusive Hillis-Steele scan over 256 bins (parallel, 8 steps)
        for (int s = 1; s < 256; s <<= 1) {
            const int v = (tid >= s) ? cnt[tid - s] : 0;
            __syncthreads();
            cnt[tid] += v;
            __syncthreads();
        }
        const int incl = cnt[tid];
        const int excl = incl - orig;
        if (rem > excl && rem <= incl) {   // unique tid (orig>0 there)
            bc_bin = tid;
            bc_rem = rem - excl;
        }
        __syncthreads();
        prefix |= ((unsigned)bc_bin) << shift;
        rem = bc_rem;
        __syncthreads();
    }
    // prefix = T (exact bits of KSEL-th smallest d2); rem = #ties to take.

    float local = 0.0f;
#pragma unroll
    for (int p = 0; p < 4; ++p)
        if (uu[p] < prefix) local += __builtin_amdgcn_sqrtf(__uint_as_float(uu[p]));
#pragma unroll
    for (int off = 32; off > 0; off >>= 1) local += __shfl_down(local, off);
    if ((tid & 63) == 0) wred[tid >> 6] = local;

    float r = (tid < MC) ? repel_part[b * MC + tid] : 0.0f;
#pragma unroll
    for (int off = 32; off > 0; off >>= 1) r += __shfl_down(r, off);
    if ((tid & 63) == 0) wred2[tid >> 6] = r;
    __syncthreads();

    if (tid == 0) {
        const float total = wred[0] + wred[1] + wred[2] + wred[3]
                          + (float)rem * __builtin_amdgcn_sqrtf(__uint_as_float(prefix));
        const float rp = wred2[0] + wred2[1] + wred2[2] + wred2[3];
        out[b] = 10.0f * (total / (float)KSEL) + 5.0f * rp;
    }
}

extern "C" void kernel_launch(void* const* d_in, const int* in_sizes, int n_in,
                              void* d_out, int out_size, void* d_ws, size_t ws_size,
                              hipStream_t stream) {
    const float* binder = (const float*)d_in[0];   // [16,1024,3] fp32
    const float* target = (const float*)d_in[1];   // [8192,3]   fp32
    float* out = (float*)d_out;                    // [16]       fp32

    unsigned* min_u   = (unsigned*)d_ws;                               // 64 KB
    float* repel_part = (float*)((char*)d_ws + (size_t)BB * NN * sizeof(unsigned));

    // 0xFFFFFFFF == uint +inf for the atomicMin fold (capture-safe memset)
    hipMemsetAsync(min_u, 0xFF, (size_t)BB * NN * sizeof(unsigned), stream);

    dim3 g1(MC, BB);   // 128 x 16 = 2048 blocks -> 8 blocks/CU
    binder_pair_kernel<<<g1, 256, 0, stream>>>(binder, target, min_u, repel_part);
    binder_reduce_kernel<<<BB, 256, 0, stream>>>(min_u, repel_part, out);
}